// Round 7
// baseline (720.063 us; speedup 1.0000x reference)
//
#include <hip/hip_runtime.h>
#include <cstddef>
#include <cstdint>

#define B_ 32
#define N_ 8192
#define D_ 64
#define H_ 128
#define S_ 16
// softmax in exp2 domain: logit_e2 = (2*dot - |s|^2) * (1/tau) * log2(e)
#define L2SCALE 14.426950408889634f

typedef unsigned short ushort_t;
typedef __attribute__((ext_vector_type(8))) short short8;
typedef __attribute__((ext_vector_type(4))) float f32x4;

#define NCHUNK 256                 // n per attn block
#define NBLK   (N_ / NCHUNK)       // 32 chunks per batch
#define PSTRIDE 264                // P row stride in shorts (256+8)

#define W1T_STR 72                 // u16 row stride (144 B, 16-aligned)
#define W2T_STR 136                // u16 row stride (272 B, 16-aligned)

// gelu via A&S 7.1.26 erf approx (|eps| <= 1.5e-7), ~15 VALU inst vs ~70 for libm erff
__device__ __forceinline__ float gelu_fast(float x){
    float z = fabsf(x) * 0.70710678118654752f;
    float t = 1.0f / fmaf(0.3275911f, z, 1.0f);
    float p = t*(0.254829592f + t*(-0.284496736f + t*(1.421413741f +
              t*(-1.453152027f + t*1.061405429f))));
    float e = __expf(-z*z);
    float erf_abs = 1.0f - p*e;
    float er = copysignf(erf_abs, x);
    return 0.5f * x * (1.0f + er);
}
__device__ __forceinline__ ushort_t f2bf(float f){
    unsigned u = __float_as_uint(f);
    unsigned r = (u + 0x7FFF + ((u >> 16) & 1)) >> 16;   // RNE
    return (ushort_t)r;
}
__device__ __forceinline__ float bf2f(ushort_t h){
    return __uint_as_float(((unsigned)h) << 16);
}

// ---------------------------------------------------------------------------
// gemm1: h = gelu(LN1(x@w1 + b1)) -> h_hi/h_lo bf16 split, [row][128].
// Block: 256 thr / 4 waves, 128 rows (wave w: 2 row-tiles). Grid 2048.
// ---------------------------------------------------------------------------
__global__ __launch_bounds__(256) void gemm1_kernel(
    const float* __restrict__ x, const float* __restrict__ w1, const float* __restrict__ b1,
    const float* __restrict__ ln1g, const float* __restrict__ ln1b,
    ushort_t* __restrict__ h_hi, ushort_t* __restrict__ h_lo)
{
    __shared__ ushort_t w1t_hi[128*W1T_STR];   // 18432 B
    __shared__ ushort_t w1t_lo[128*W1T_STR];

    const int tid  = threadIdx.x;
    const int w    = tid >> 6;
    const int l    = tid & 63;
    const int ln   = l & 15;
    const int quad = l >> 4;
    const size_t n0 = (size_t)blockIdx.x * 128;

    for (int i = tid; i < 8192; i += 256){
        int k = i >> 7, hc = i & 127;
        float v = w1[i];
        ushort_t hi = f2bf(v);
        w1t_hi[hc*W1T_STR + k] = hi;
        w1t_lo[hc*W1T_STR + k] = f2bf(v - bf2f(hi));
    }
    __syncthreads();

    for (int tt = 0; tt < 2; ++tt){
        const size_t row = n0 + (size_t)(w*2 + tt)*16 + ln;
        const float* xr = x + row*64;

        short8 bxh[2], bxl[2];
        #pragma unroll
        for (int kc = 0; kc < 2; ++kc){
            float4 a0 = *(const float4*)(xr + kc*32 + quad*8);
            float4 a1 = *(const float4*)(xr + kc*32 + quad*8 + 4);
            float v[8] = {a0.x,a0.y,a0.z,a0.w,a1.x,a1.y,a1.z,a1.w};
            #pragma unroll
            for (int j=0;j<8;++j){
                ushort_t hi = f2bf(v[j]);
                bxh[kc][j] = (short)hi;
                bxl[kc][j] = (short)f2bf(v[j] - bf2f(hi));
            }
        }

        f32x4 acc[8];
        #pragma unroll
        for (int ht=0;ht<8;++ht) acc[ht] = (f32x4){0.f,0.f,0.f,0.f};

        #pragma unroll
        for (int ht = 0; ht < 8; ++ht){
            #pragma unroll
            for (int kc = 0; kc < 2; ++kc){
                short8 ah = *(const short8*)&w1t_hi[(ht*16+ln)*W1T_STR + kc*32 + quad*8];
                short8 al = *(const short8*)&w1t_lo[(ht*16+ln)*W1T_STR + kc*32 + quad*8];
                acc[ht] = __builtin_amdgcn_mfma_f32_16x16x32_bf16(ah, bxh[kc], acc[ht], 0,0,0);
                acc[ht] = __builtin_amdgcn_mfma_f32_16x16x32_bf16(ah, bxl[kc], acc[ht], 0,0,0);
                acc[ht] = __builtin_amdgcn_mfma_f32_16x16x32_bf16(al, bxh[kc], acc[ht], 0,0,0);
            }
        }

        float vals[8][4];
        float s1 = 0.f, sq = 0.f;
        #pragma unroll
        for (int ht=0;ht<8;++ht){
            float bb[4]; *(float4*)bb = *(const float4*)(b1 + ht*16 + quad*4);
            #pragma unroll
            for (int r=0;r<4;++r){
                float v = acc[ht][r] + bb[r];
                vals[ht][r] = v; s1 += v; sq += v*v;
            }
        }
        s1 += __shfl_xor(s1,16); s1 += __shfl_xor(s1,32);
        sq += __shfl_xor(sq,16); sq += __shfl_xor(sq,32);
        float mean = s1 * (1.f/128.f);
        float var  = sq * (1.f/128.f) - mean*mean;
        float rs   = 1.f / sqrtf(var + 1e-5f);

        #pragma unroll
        for (int ht=0;ht<8;++ht){
            float gg[4]; *(float4*)gg = *(const float4*)(ln1g + ht*16 + quad*4);
            float be[4]; *(float4*)be = *(const float4*)(ln1b + ht*16 + quad*4);
            ushort_t oh[4], ol[4];
            #pragma unroll
            for (int r=0;r<4;++r){
                float t  = (vals[ht][r]-mean)*rs*gg[r] + be[r];
                float ge = gelu_fast(t);
                ushort_t hi = f2bf(ge);
                oh[r] = hi;
                ol[r] = f2bf(ge - bf2f(hi));
            }
            size_t off = row*128 + ht*16 + quad*4;
            *(ushort4*)(h_hi + off) = make_ushort4(oh[0],oh[1],oh[2],oh[3]);
            *(ushort4*)(h_lo + off) = make_ushort4(ol[0],ol[1],ol[2],ol[3]);
        }
    }
}

// ---------------------------------------------------------------------------
// gemm2: f = LN2(h@w2 + b2) written IN PLACE over h.
// Block: 256 thr / 4 waves, 128 rows (wave w: 2 row-tiles). Grid 2048.
// ---------------------------------------------------------------------------
__global__ __launch_bounds__(256) void gemm2_kernel(
    ushort_t* __restrict__ buf_hi, ushort_t* __restrict__ buf_lo,
    const float* __restrict__ w2, const float* __restrict__ b2,
    const float* __restrict__ ln2g, const float* __restrict__ ln2b)
{
    __shared__ ushort_t w2t_hi[128*W2T_STR];   // 34816 B
    __shared__ ushort_t w2t_lo[128*W2T_STR];

    const int tid  = threadIdx.x;
    const int w    = tid >> 6;
    const int l    = tid & 63;
    const int ln   = l & 15;
    const int quad = l >> 4;
    const size_t n0 = (size_t)blockIdx.x * 128;

    for (int i = tid; i < 16384; i += 256){
        int k = i >> 7, hc = i & 127;
        float v = w2[i];
        ushort_t hi = f2bf(v);
        w2t_hi[hc*W2T_STR + k] = hi;
        w2t_lo[hc*W2T_STR + k] = f2bf(v - bf2f(hi));
    }
    __syncthreads();

    size_t row[2];
    row[0] = n0 + (size_t)(w*2 + 0)*16 + ln;
    row[1] = n0 + (size_t)(w*2 + 1)*16 + ln;

    f32x4 acc[2][8];
    #pragma unroll
    for (int t2=0;t2<2;++t2)
        #pragma unroll
        for (int ht=0;ht<8;++ht) acc[t2][ht] = (f32x4){0.f,0.f,0.f,0.f};

    #pragma unroll
    for (int kc = 0; kc < 4; ++kc){
        short8 bh[2], bl[2];
        #pragma unroll
        for (int t2=0;t2<2;++t2){
            bh[t2] = *(const short8*)(buf_hi + row[t2]*128 + kc*32 + quad*8);
            bl[t2] = *(const short8*)(buf_lo + row[t2]*128 + kc*32 + quad*8);
        }
        #pragma unroll
        for (int ht = 0; ht < 8; ++ht){
            short8 ah = *(const short8*)&w2t_hi[(ht*16+ln)*W2T_STR + kc*32 + quad*8];
            short8 al = *(const short8*)&w2t_lo[(ht*16+ln)*W2T_STR + kc*32 + quad*8];
            #pragma unroll
            for (int t2=0;t2<2;++t2){
                acc[t2][ht] = __builtin_amdgcn_mfma_f32_16x16x32_bf16(ah, bh[t2], acc[t2][ht], 0,0,0);
                acc[t2][ht] = __builtin_amdgcn_mfma_f32_16x16x32_bf16(ah, bl[t2], acc[t2][ht], 0,0,0);
                acc[t2][ht] = __builtin_amdgcn_mfma_f32_16x16x32_bf16(al, bh[t2], acc[t2][ht], 0,0,0);
            }
        }
    }

    #pragma unroll
    for (int t2=0;t2<2;++t2){
        float vals[8][4];
        float s1 = 0.f, sq = 0.f;
        #pragma unroll
        for (int ht=0;ht<8;++ht){
            float bb[4]; *(float4*)bb = *(const float4*)(b2 + ht*16 + quad*4);
            #pragma unroll
            for (int r=0;r<4;++r){
                float v = acc[t2][ht][r] + bb[r];
                vals[ht][r] = v; s1 += v; sq += v*v;
            }
        }
        s1 += __shfl_xor(s1,16); s1 += __shfl_xor(s1,32);
        sq += __shfl_xor(sq,16); sq += __shfl_xor(sq,32);
        float mean = s1 * (1.f/128.f);
        float var  = sq * (1.f/128.f) - mean*mean;
        float rs   = 1.f / sqrtf(var + 1e-5f);
        #pragma unroll
        for (int ht=0;ht<8;++ht){
            float gg[4]; *(float4*)gg = *(const float4*)(ln2g + ht*16 + quad*4);
            float be[4]; *(float4*)be = *(const float4*)(ln2b + ht*16 + quad*4);
            ushort_t oh[4], ol[4];
            #pragma unroll
            for (int r=0;r<4;++r){
                float o = (vals[ht][r]-mean)*rs*gg[r] + be[r];
                ushort_t hi = f2bf(o);
                oh[r] = hi;
                ol[r] = f2bf(o - bf2f(hi));
            }
            size_t off = row[t2]*128 + ht*16 + quad*4;
            *(ushort4*)(buf_hi + off) = make_ushort4(oh[0],oh[1],oh[2],oh[3]);
            *(ushort4*)(buf_lo + off) = make_ushort4(ol[0],ol[1],ol[2],ol[3]);
        }
    }
}

__global__ void init_slots(const float* __restrict__ mu, float* __restrict__ slots){
    int i = blockIdx.x * 256 + threadIdx.x;
    slots[i] = mu[i & 2047];
}

// ---------------------------------------------------------------------------
// attn (v6): 256 thr / 4 waves, 256-n chunk, grid 1024. LB(256,3) -> 3
// blocks/CU co-resident. Same per-wave work as v5; occupancy/latency play.
// ---------------------------------------------------------------------------
__global__ __launch_bounds__(256, 3) void attn_kernel(
    const ushort_t* __restrict__ f_hi, const ushort_t* __restrict__ f_lo,
    const float* __restrict__ slots,
    float* __restrict__ pn, float* __restrict__ pd,
    float* __restrict__ attn_out, const int write_attn)
{
    __shared__ ushort_t P_hi[16*PSTRIDE];   // 8448 B
    __shared__ ushort_t P_lo[16*PSTRIDE];
    __shared__ float    s2buf[16];
    __shared__ float    den_red[16];

    const int tid  = threadIdx.x;
    const int w    = tid >> 6;
    const int l    = tid & 63;
    const int ln   = l & 15;
    const int quad = l >> 4;
    const int b    = blockIdx.x >> 5;
    const int nc   = blockIdx.x & 31;
    const int n0   = nc * NCHUNK;

    if (tid < 16) den_red[tid] = 0.f;

    short8 sa_hi[4], sa_lo[4];
    float q2 = 0.f;
    {
        const float* sp = slots + ((size_t)(b*16 + ln))*128 + quad*8;
        #pragma unroll
        for (int ks=0; ks<4; ++ks){
            float4 v0 = *(const float4*)(sp + ks*32);
            float4 v1 = *(const float4*)(sp + ks*32 + 4);
            float v[8] = {v0.x,v0.y,v0.z,v0.w,v1.x,v1.y,v1.z,v1.w};
            #pragma unroll
            for (int j=0;j<8;++j){
                q2 += v[j]*v[j];
                ushort_t hi = f2bf(v[j]);
                float lo = v[j] - bf2f(hi);
                sa_hi[ks][j] = (short)hi;
                sa_lo[ks][j] = (short)f2bf(lo);
            }
        }
    }
    q2 += __shfl_xor(q2, 16);
    q2 += __shfl_xor(q2, 32);
    if (tid < 16) s2buf[tid] = q2;
    __syncthreads();

    float s2v[4];
    #pragma unroll
    for (int r=0;r<4;++r) s2v[r] = s2buf[quad*4 + r];

    float den_acc[4] = {0.f,0.f,0.f,0.f};
    const size_t fbase = (size_t)b*N_ + n0;

    #pragma unroll
    for (int t2=0; t2<4; ++t2){
        const int t  = w*4 + t2;
        const int nl = t*16 + ln;                 // [0,256)
        const size_t rowoff = (fbase + nl) * 128;

        short8 fh[4], fl[4];
        #pragma unroll
        for (int ks=0; ks<4; ++ks){
            fh[ks] = *(const short8*)(f_hi + rowoff + ks*32 + quad*8);
            fl[ks] = *(const short8*)(f_lo + rowoff + ks*32 + quad*8);
        }

        f32x4 d = {0.f,0.f,0.f,0.f};
        #pragma unroll
        for (int ks=0;ks<4;++ks) d = __builtin_amdgcn_mfma_f32_16x16x32_bf16(sa_hi[ks], fh[ks], d, 0,0,0);
        #pragma unroll
        for (int ks=0;ks<4;++ks) d = __builtin_amdgcn_mfma_f32_16x16x32_bf16(sa_hi[ks], fl[ks], d, 0,0,0);
        #pragma unroll
        for (int ks=0;ks<4;++ks) d = __builtin_amdgcn_mfma_f32_16x16x32_bf16(sa_lo[ks], fh[ks], d, 0,0,0);

        float L[4];
        #pragma unroll
        for (int r=0;r<4;++r) L[r] = (2.f*d[r] - s2v[r]) * L2SCALE;
        float mx = fmaxf(fmaxf(L[0],L[1]), fmaxf(L[2],L[3]));
        mx = fmaxf(mx, __shfl_xor(mx, 16));
        mx = fmaxf(mx, __shfl_xor(mx, 32));
        float e[4];
        float z = 0.f;
        #pragma unroll
        for (int r=0;r<4;++r){ e[r] = exp2f(L[r] - mx); z += e[r]; }
        z += __shfl_xor(z, 16);
        z += __shfl_xor(z, 32);
        float rz = 1.f / z;
        #pragma unroll
        for (int r=0;r<4;++r){
            float p = e[r] * rz;
            den_acc[r] += p;
            if (write_attn)
                attn_out[((size_t)(b*16 + quad*4 + r))*N_ + n0 + nl] = p;
            ushort_t ph = f2bf(p);
            float plr = p - bf2f(ph);
            P_hi[(quad*4+r)*PSTRIDE + nl] = ph;
            P_lo[(quad*4+r)*PSTRIDE + nl] = f2bf(plr);
        }
    }

    #pragma unroll
    for (int m=1; m<16; m<<=1){
        #pragma unroll
        for (int r=0;r<4;++r) den_acc[r] += __shfl_xor(den_acc[r], m);
    }
    if (ln == 0){
        #pragma unroll
        for (int r=0;r<4;++r) atomicAdd(&den_red[quad*4 + r], den_acc[r]);
    }
    __syncthreads();

    // phase 2: wave w owns h-tiles {2w, 2w+1}
    #pragma unroll
    for (int t2=0; t2<2; ++t2){
        const int ht = w*2 + t2;
        f32x4 dacc = {0.f,0.f,0.f,0.f};
        #pragma unroll 2
        for (int ks=0; ks<8; ++ks){
            short8 pah = *(const short8*)(&P_hi[ln*PSTRIDE + ks*32 + quad*8]);
            short8 pal = *(const short8*)(&P_lo[ln*PSTRIDE + ks*32 + quad*8]);
            short8 fbh, fbl;
            #pragma unroll
            for (int j=0;j<8;++j){
                size_t go = (fbase + (size_t)(ks*32 + quad*8 + j))*128 + ht*16 + ln;
                fbh[j] = (short)f_hi[go];
                fbl[j] = (short)f_lo[go];
            }
            dacc = __builtin_amdgcn_mfma_f32_16x16x32_bf16(pah, fbh, dacc, 0,0,0);
            dacc = __builtin_amdgcn_mfma_f32_16x16x32_bf16(pal, fbh, dacc, 0,0,0);
            dacc = __builtin_amdgcn_mfma_f32_16x16x32_bf16(pah, fbl, dacc, 0,0,0);
        }
        float* dst = pn + (size_t)blockIdx.x * 2048;
        #pragma unroll
        for (int r=0;r<4;++r)
            dst[(quad*4+r)*128 + ht*16 + ln] = dacc[r];
    }
    if (tid < 16) pd[blockIdx.x*16 + tid] = den_red[tid];
}

// ---------------------------------------------------------------------------
// update: GRU + LN + MLP + fold of the 32 per-chunk partials.
// ---------------------------------------------------------------------------
__global__ __launch_bounds__(256) void update_kernel(
    const float* __restrict__ pn, const float* __restrict__ pd,
    float* __restrict__ slots,
    const float* __restrict__ gwi, const float* __restrict__ gwh,
    const float* __restrict__ gbi, const float* __restrict__ gbh,
    const float* __restrict__ mw1, const float* __restrict__ mb1,
    const float* __restrict__ mw2, const float* __restrict__ mb2,
    const float* __restrict__ ng, const float* __restrict__ nbv,
    float* __restrict__ out_slots, const int write_out)
{
    __shared__ float us[512], sl[512], gbuf[3072], nbuf[512], lnb[512], qb[512];
    const int tid  = threadIdx.x;
    const int row0 = blockIdx.x * 4;

    for (int i = tid; i < 512; i += 256){
        int r = i >> 7, h = i & 127;
        int grow = row0 + r;
        int bb = grow >> 4, ss = grow & 15;
        float sum = 0.f, dv = 0.f;
        #pragma unroll 4
        for (int c = 0; c < NBLK; ++c)
            sum += pn[((size_t)(bb*NBLK + c))*2048 + ss*128 + h];
        #pragma unroll
        for (int c = 0; c < NBLK; ++c)
            dv += pd[(bb*NBLK + c)*16 + ss];
        us[i] = sum / (dv + 1e-8f);
        sl[i] = slots[(size_t)grow*128 + h];
    }
    __syncthreads();

    for (int idx = tid; idx < 3072; idx += 256){
        int which = idx >= 1536;
        int rem   = idx - which*1536;
        int r     = rem / 384;
        int o     = rem - r*384;
        const float* W   = which ? gwh : gwi;
        const float* bb  = which ? gbh : gbi;
        const float* src = (which ? sl : us) + r*128;
        float a = bb[o];
        const float4* Wr = (const float4*)(W + (size_t)o*128);
        #pragma unroll 8
        for (int k4=0;k4<32;++k4){
            float4 wv = Wr[k4];
            float4 sv = *(const float4*)(src + 4*k4);
            a += sv.x*wv.x + sv.y*wv.y + sv.z*wv.z + sv.w*wv.w;
        }
        gbuf[idx] = a;
    }
    __syncthreads();

    for (int i = tid; i < 512; i += 256){
        int r = i >> 7, h = i & 127;
        float ir  = gbuf[r*384 + h];
        float iz  = gbuf[r*384 + 128 + h];
        float in_ = gbuf[r*384 + 256 + h];
        float hr  = gbuf[1536 + r*384 + h];
        float hz  = gbuf[1536 + r*384 + 128 + h];
        float hn  = gbuf[1536 + r*384 + 256 + h];
        float rg = 1.f/(1.f + __expf(-(ir+hr)));
        float zg = 1.f/(1.f + __expf(-(iz+hz)));
        float nn = tanhf(in_ + rg*hn);
        nbuf[i] = (1.f - zg)*nn + zg*sl[i];
    }
    __syncthreads();

    {
        int wv = tid >> 6, ll = tid & 63;
        float v0 = nbuf[wv*128 + ll], v1 = nbuf[wv*128 + 64 + ll];
        float s1 = v0 + v1, sq = v0*v0 + v1*v1;
        #pragma unroll
        for (int m=1; m<64; m<<=1){ s1 += __shfl_xor(s1,m); sq += __shfl_xor(sq,m); }
        float mean = s1*(1.f/128.f), var = sq*(1.f/128.f) - mean*mean;
        float rs = 1.f/sqrtf(var + 1e-5f);
        lnb[wv*128 + ll]      = (v0-mean)*rs*ng[ll] + nbv[ll];
        lnb[wv*128 + 64 + ll] = (v1-mean)*rs*ng[64+ll] + nbv[64+ll];
    }
    __syncthreads();

    for (int i = tid; i < 512; i += 256){
        int r = i >> 7, o = i & 127;
        float a = mb1[o];
        const float* lr = lnb + r*128;
        #pragma unroll 8
        for (int k=0;k<128;++k) a += lr[k] * mw1[(size_t)k*128 + o];
        qb[i] = gelu_fast(a);
    }
    __syncthreads();

    for (int i = tid; i < 512; i += 256){
        int r = i >> 7, h = i & 127;
        float a = mb2[h];
        const float* qr = qb + r*128;
        #pragma unroll 8
        for (int k=0;k<128;++k) a += qr[k] * mw2[(size_t)k*128 + h];
        float ov = nbuf[i] + 0.2f*a;
        int grow = row0 + r;
        slots[(size_t)grow*128 + h] = ov;
        if (write_out) out_slots[(size_t)grow*128 + h] = ov;
    }
}

// ---------------------------------------------------------------------------
extern "C" void kernel_launch(void* const* d_in, const int* in_sizes, int n_in,
                              void* d_out, int out_size, void* d_ws, size_t ws_size,
                              hipStream_t stream)
{
    const float* x    = (const float*)d_in[0];
    const float* w1   = (const float*)d_in[1];
    const float* b1   = (const float*)d_in[2];
    const float* ln1g = (const float*)d_in[3];
    const float* ln1b = (const float*)d_in[4];
    const float* w2   = (const float*)d_in[5];
    const float* b2   = (const float*)d_in[6];
    const float* ln2g = (const float*)d_in[7];
    const float* ln2b = (const float*)d_in[8];
    const float* smu  = (const float*)d_in[9];
    const float* gwi  = (const float*)d_in[10];
    const float* gwh  = (const float*)d_in[11];
    const float* gbi  = (const float*)d_in[12];
    const float* gbh  = (const float*)d_in[13];
    const float* mw1  = (const float*)d_in[14];
    const float* mb1  = (const float*)d_in[15];
    const float* mw2  = (const float*)d_in[16];
    const float* mb2  = (const float*)d_in[17];
    const float* ng   = (const float*)d_in[18];
    const float* nbv  = (const float*)d_in[19];

    float* out_slots = (float*)d_out;
    float* out_attn  = (float*)d_out + (size_t)B_*S_*H_;

    ushort_t* buf_hi = (ushort_t*)d_ws;
    ushort_t* buf_lo = buf_hi + (size_t)B_*N_*H_;
    float* slots = (float*)(buf_lo + (size_t)B_*N_*H_);
    float* pn    = slots + B_*S_*H_;                 // [1024 blocks][2048]
    float* pd    = pn + (size_t)(B_*NBLK)*2048;      // [1024 blocks][16]

    gemm1_kernel<<<dim3(2048), dim3(256), 0, stream>>>(
        x, w1, b1, ln1g, ln1b, buf_hi, buf_lo);
    gemm2_kernel<<<dim3(2048), dim3(256), 0, stream>>>(
        buf_hi, buf_lo, w2, b2, ln2g, ln2b);
    init_slots<<<dim3(256), dim3(256), 0, stream>>>(smu, slots);

    for (int it = 0; it < 3; ++it){
        attn_kernel<<<dim3(B_*NBLK), dim3(256), 0, stream>>>(
            buf_hi, buf_lo, slots, pn, pd, out_attn, (it==2) ? 1 : 0);
        update_kernel<<<dim3(128), dim3(256), 0, stream>>>(
            pn, pd, slots, gwi, gwh, gbi, gbh, mw1, mb1, mw2, mb2, ng, nbv,
            out_slots, (it==2) ? 1 : 0);
    }
}

// Round 8
// 618.118 us; speedup vs baseline: 1.1649x; 1.1649x over previous
//
#include <hip/hip_runtime.h>
#include <cstddef>
#include <cstdint>

#define B_ 32
#define N_ 8192
#define D_ 64
#define H_ 128
#define S_ 16
// softmax in exp2 domain: logit_e2 = (2*dot - |s|^2) * (1/tau) * log2(e)
#define L2SCALE 14.426950408889634f

typedef unsigned short ushort_t;
typedef __attribute__((ext_vector_type(8))) short short8;
typedef __attribute__((ext_vector_type(4))) short short4v;
typedef __attribute__((ext_vector_type(4))) float f32x4;

#define NCHUNK 256                 // n per attn block (2 halves of 128)
#define NBLK   (N_ / NCHUNK)       // 32 chunks per batch
#define PSTR   140                 // P row stride (u16), 4-mult, bank-spread
#define FTSTR  132                 // fT row stride (u16), 4-mult, bank-spread
#define HSTR   132                 // LDS h row stride (u16)

// gelu via A&S 7.1.26 erf approx (|eps| <= 1.5e-7)
__device__ __forceinline__ float gelu_fast(float x){
    float z = fabsf(x) * 0.70710678118654752f;
    float t = 1.0f / fmaf(0.3275911f, z, 1.0f);
    float p = t*(0.254829592f + t*(-0.284496736f + t*(1.421413741f +
              t*(-1.453152027f + t*1.061405429f))));
    float e = __expf(-z*z);
    float er = copysignf(1.0f - p*e, x);
    return 0.5f * x * (1.0f + er);
}
__device__ __forceinline__ ushort_t f2bf(float f){
    unsigned u = __float_as_uint(f);
    unsigned r = (u + 0x7FFF + ((u >> 16) & 1)) >> 16;   // RNE
    return (ushort_t)r;
}
__device__ __forceinline__ float bf2f(ushort_t h){
    return __uint_as_float(((unsigned)h) << 16);
}
// 8-u16 load from 8B-aligned (not 16B) address via two b64s
__device__ __forceinline__ short8 ld8x2(const ushort_t* p){
    short4v a = *(const short4v*)p;
    short4v b = *(const short4v*)(p + 4);
    return __builtin_shufflevector(a, b, 0,1,2,3,4,5,6,7);
}

// ---------------------------------------------------------------------------
// prep: split-transpose w1 -> w1T[h][k] (hi/lo), w2 -> w2T[h][k] (hi/lo).
// ---------------------------------------------------------------------------
__global__ void prep_kernel(const float* __restrict__ w1, const float* __restrict__ w2,
                            ushort_t* __restrict__ w1t_hi, ushort_t* __restrict__ w1t_lo,
                            ushort_t* __restrict__ w2t_hi, ushort_t* __restrict__ w2t_lo)
{
    int i = blockIdx.x * 256 + threadIdx.x;      // grid 64*256 = 16384
    if (i < 8192){
        int k = i >> 7, h = i & 127;
        float v = w1[i];
        ushort_t hi = f2bf(v);
        w1t_hi[h*64 + k] = hi;
        w1t_lo[h*64 + k] = f2bf(v - bf2f(hi));
    }
    {
        int k = i >> 7, h = i & 127;
        float v = w2[i];
        ushort_t hi = f2bf(v);
        w2t_hi[h*128 + k] = hi;
        w2t_lo[h*128 + k] = f2bf(v - bf2f(hi));
    }
}

// ---------------------------------------------------------------------------
// fused feats: f = LN2( gelu(LN1(x@w1+b1)) @ w2 + b2 ) -> f_hi/f_lo.
// h never touches HBM (lives in LDS). Weight A-frags stream from L2 (wT).
// Block: 256 thr / 4 waves, 128 rows. Grid 2048.
// ---------------------------------------------------------------------------
__global__ __launch_bounds__(256) void feats_kernel(
    const float* __restrict__ x,
    const ushort_t* __restrict__ w1t_hi, const ushort_t* __restrict__ w1t_lo,
    const ushort_t* __restrict__ w2t_hi, const ushort_t* __restrict__ w2t_lo,
    const float* __restrict__ b1, const float* __restrict__ ln1g, const float* __restrict__ ln1b,
    const float* __restrict__ b2, const float* __restrict__ ln2g, const float* __restrict__ ln2b,
    ushort_t* __restrict__ f_hi, ushort_t* __restrict__ f_lo)
{
    __shared__ ushort_t hsh[128*HSTR];   // 33792 B
    __shared__ ushort_t hsl[128*HSTR];

    const int tid  = threadIdx.x;
    const int w    = tid >> 6;
    const int l    = tid & 63;
    const int ln   = l & 15;
    const int quad = l >> 4;
    const size_t n0 = (size_t)blockIdx.x * 128;

    // ---- phase A: h = gelu(LN1(x@w1+b1)) -> LDS ----
    for (int t2 = 0; t2 < 2; ++t2){
        const int rloc = (w*2 + t2)*16 + ln;
        const size_t row = n0 + rloc;
        const float* xr = x + row*64;

        short8 bxh[2], bxl[2];
        #pragma unroll
        for (int kc = 0; kc < 2; ++kc){
            float4 a0 = *(const float4*)(xr + kc*32 + quad*8);
            float4 a1 = *(const float4*)(xr + kc*32 + quad*8 + 4);
            float v[8] = {a0.x,a0.y,a0.z,a0.w,a1.x,a1.y,a1.z,a1.w};
            #pragma unroll
            for (int j=0;j<8;++j){
                ushort_t hi = f2bf(v[j]);
                bxh[kc][j] = (short)hi;
                bxl[kc][j] = (short)f2bf(v[j] - bf2f(hi));
            }
        }

        f32x4 acc[8];
        #pragma unroll
        for (int ht=0;ht<8;++ht) acc[ht] = (f32x4){0.f,0.f,0.f,0.f};
        #pragma unroll
        for (int ht = 0; ht < 8; ++ht){
            #pragma unroll
            for (int kc = 0; kc < 2; ++kc){
                short8 ah = *(const short8*)&w1t_hi[(ht*16+ln)*64 + kc*32 + quad*8];
                short8 al = *(const short8*)&w1t_lo[(ht*16+ln)*64 + kc*32 + quad*8];
                acc[ht] = __builtin_amdgcn_mfma_f32_16x16x32_bf16(ah, bxh[kc], acc[ht], 0,0,0);
                acc[ht] = __builtin_amdgcn_mfma_f32_16x16x32_bf16(ah, bxl[kc], acc[ht], 0,0,0);
                acc[ht] = __builtin_amdgcn_mfma_f32_16x16x32_bf16(al, bxh[kc], acc[ht], 0,0,0);
            }
        }

        float vals[8][4];
        float s1 = 0.f, sq = 0.f;
        #pragma unroll
        for (int ht=0;ht<8;++ht){
            float bb[4]; *(float4*)bb = *(const float4*)(b1 + ht*16 + quad*4);
            #pragma unroll
            for (int r=0;r<4;++r){
                float v = acc[ht][r] + bb[r];
                vals[ht][r] = v; s1 += v; sq += v*v;
            }
        }
        s1 += __shfl_xor(s1,16); s1 += __shfl_xor(s1,32);
        sq += __shfl_xor(sq,16); sq += __shfl_xor(sq,32);
        float mean = s1 * (1.f/128.f);
        float var  = sq * (1.f/128.f) - mean*mean;
        float rs   = 1.f / sqrtf(var + 1e-5f);

        #pragma unroll
        for (int ht=0;ht<8;++ht){
            float gg[4]; *(float4*)gg = *(const float4*)(ln1g + ht*16 + quad*4);
            float be[4]; *(float4*)be = *(const float4*)(ln1b + ht*16 + quad*4);
            short4v oh, ol;
            #pragma unroll
            for (int r=0;r<4;++r){
                float t  = (vals[ht][r]-mean)*rs*gg[r] + be[r];
                float ge = gelu_fast(t);
                ushort_t hi = f2bf(ge);
                oh[r] = (short)hi;
                ol[r] = (short)f2bf(ge - bf2f(hi));
            }
            *(short4v*)&hsh[rloc*HSTR + ht*16 + quad*4] = oh;
            *(short4v*)&hsl[rloc*HSTR + ht*16 + quad*4] = ol;
        }
    }
    __syncthreads();

    // ---- phase B: f = LN2(h@w2+b2) -> global ----
    for (int t2 = 0; t2 < 2; ++t2){
        const int rloc = (w*2 + t2)*16 + ln;
        const size_t row = n0 + rloc;

        f32x4 acc2[8];
        #pragma unroll
        for (int ht=0;ht<8;++ht) acc2[ht] = (f32x4){0.f,0.f,0.f,0.f};

        #pragma unroll
        for (int kc = 0; kc < 4; ++kc){
            short8 bh = ld8x2(&hsh[rloc*HSTR + kc*32 + quad*8]);
            short8 bl = ld8x2(&hsl[rloc*HSTR + kc*32 + quad*8]);
            #pragma unroll
            for (int ht = 0; ht < 8; ++ht){
                short8 ah = *(const short8*)&w2t_hi[(ht*16+ln)*128 + kc*32 + quad*8];
                short8 al = *(const short8*)&w2t_lo[(ht*16+ln)*128 + kc*32 + quad*8];
                acc2[ht] = __builtin_amdgcn_mfma_f32_16x16x32_bf16(ah, bh, acc2[ht], 0,0,0);
                acc2[ht] = __builtin_amdgcn_mfma_f32_16x16x32_bf16(ah, bl, acc2[ht], 0,0,0);
                acc2[ht] = __builtin_amdgcn_mfma_f32_16x16x32_bf16(al, bh, acc2[ht], 0,0,0);
            }
        }

        float vals[8][4];
        float s1 = 0.f, sq = 0.f;
        #pragma unroll
        for (int ht=0;ht<8;++ht){
            float bb[4]; *(float4*)bb = *(const float4*)(b2 + ht*16 + quad*4);
            #pragma unroll
            for (int r=0;r<4;++r){
                float v = acc2[ht][r] + bb[r];
                vals[ht][r] = v; s1 += v; sq += v*v;
            }
        }
        s1 += __shfl_xor(s1,16); s1 += __shfl_xor(s1,32);
        sq += __shfl_xor(sq,16); sq += __shfl_xor(sq,32);
        float mean = s1 * (1.f/128.f);
        float var  = sq * (1.f/128.f) - mean*mean;
        float rs   = 1.f / sqrtf(var + 1e-5f);

        #pragma unroll
        for (int ht=0;ht<8;++ht){
            float gg[4]; *(float4*)gg = *(const float4*)(ln2g + ht*16 + quad*4);
            float be[4]; *(float4*)be = *(const float4*)(ln2b + ht*16 + quad*4);
            ushort_t oh[4], ol[4];
            #pragma unroll
            for (int r=0;r<4;++r){
                float o = (vals[ht][r]-mean)*rs*gg[r] + be[r];
                ushort_t hi = f2bf(o);
                oh[r] = hi;
                ol[r] = f2bf(o - bf2f(hi));
            }
            size_t off = row*128 + ht*16 + quad*4;
            *(ushort4*)(f_hi + off) = make_ushort4(oh[0],oh[1],oh[2],oh[3]);
            *(ushort4*)(f_lo + off) = make_ushort4(ol[0],ol[1],ol[2],ol[3]);
        }
    }
}

__global__ void init_slots(const float* __restrict__ mu, float* __restrict__ slots){
    int i = blockIdx.x * 256 + threadIdx.x;
    slots[i] = mu[i & 2047];
}

// ---------------------------------------------------------------------------
// attn (v8): 256 thr / 4 waves, 256-n chunk in TWO 128-n halves. Phase 1
// loads F fragments (only global read), computes logits+softmax AND scatters
// the same fragments into an LDS transpose fT[h][n]. Phase 2 (PV) runs
// entirely from LDS: A = fT rows, B = P^T. No global re-read, no atomics.
// ---------------------------------------------------------------------------
__global__ __launch_bounds__(256) void attn_kernel(
    const ushort_t* __restrict__ f_hi, const ushort_t* __restrict__ f_lo,
    const float* __restrict__ slots,
    float* __restrict__ pn, float* __restrict__ pd,
    float* __restrict__ attn_out, const int write_attn)
{
    __shared__ ushort_t fTh[128*FTSTR];   // 33792 B
    __shared__ ushort_t fTl[128*FTSTR];
    __shared__ ushort_t Ph[16*PSTR];      // 4480 B
    __shared__ ushort_t Pl[16*PSTR];
    __shared__ float    s2buf[16];
    __shared__ float    den_red[16];

    const int tid  = threadIdx.x;
    const int w    = tid >> 6;
    const int l    = tid & 63;
    const int ln   = l & 15;
    const int quad = l >> 4;
    const int b    = blockIdx.x >> 5;
    const int nc   = blockIdx.x & 31;
    const int n0   = nc * NCHUNK;

    if (tid < 16) den_red[tid] = 0.f;

    // slots A-fragments (hi/lo) + |s|^2
    short8 sa_hi[4], sa_lo[4];
    float q2 = 0.f;
    {
        const float* sp = slots + ((size_t)(b*16 + ln))*128 + quad*8;
        #pragma unroll
        for (int ks=0; ks<4; ++ks){
            float4 v0 = *(const float4*)(sp + ks*32);
            float4 v1 = *(const float4*)(sp + ks*32 + 4);
            float v[8] = {v0.x,v0.y,v0.z,v0.w,v1.x,v1.y,v1.z,v1.w};
            #pragma unroll
            for (int j=0;j<8;++j){
                q2 += v[j]*v[j];
                ushort_t hi = f2bf(v[j]);
                sa_hi[ks][j] = (short)hi;
                sa_lo[ks][j] = (short)f2bf(v[j] - bf2f(hi));
            }
        }
    }
    q2 += __shfl_xor(q2, 16);
    q2 += __shfl_xor(q2, 32);
    if (tid < 16) s2buf[tid] = q2;
    __syncthreads();

    float s2v[4];
    #pragma unroll
    for (int r=0;r<4;++r) s2v[r] = s2buf[quad*4 + r];

    float den_acc[4] = {0.f,0.f,0.f,0.f};
    f32x4 dacc[2];
    dacc[0] = (f32x4){0.f,0.f,0.f,0.f};
    dacc[1] = (f32x4){0.f,0.f,0.f,0.f};
    const size_t fbase = (size_t)b*N_ + n0;

    for (int hf = 0; hf < 2; ++hf){
        if (hf) __syncthreads();   // protect LDS reuse from prior phase-2 reads

        // ---- phase 1: logits + softmax + P->LDS + fT transpose->LDS ----
        #pragma unroll
        for (int t2=0; t2<2; ++t2){
            const int nl = (w*2 + t2)*16 + ln;          // [0,128)
            const size_t rowoff = (fbase + hf*128 + nl) * 128;

            short8 fh[4], fl[4];
            #pragma unroll
            for (int ks=0; ks<4; ++ks){
                fh[ks] = *(const short8*)(f_hi + rowoff + ks*32 + quad*8);
                fl[ks] = *(const short8*)(f_lo + rowoff + ks*32 + quad*8);
            }
            // transpose into LDS fT[h][n]
            #pragma unroll
            for (int ks=0; ks<4; ++ks){
                #pragma unroll
                for (int j=0;j<8;++j){
                    fTh[(ks*32 + quad*8 + j)*FTSTR + nl] = (ushort_t)fh[ks][j];
                    fTl[(ks*32 + quad*8 + j)*FTSTR + nl] = (ushort_t)fl[ks][j];
                }
            }

            f32x4 d = {0.f,0.f,0.f,0.f};
            #pragma unroll
            for (int ks=0;ks<4;++ks) d = __builtin_amdgcn_mfma_f32_16x16x32_bf16(sa_hi[ks], fh[ks], d, 0,0,0);
            #pragma unroll
            for (int ks=0;ks<4;++ks) d = __builtin_amdgcn_mfma_f32_16x16x32_bf16(sa_hi[ks], fl[ks], d, 0,0,0);
            #pragma unroll
            for (int ks=0;ks<4;++ks) d = __builtin_amdgcn_mfma_f32_16x16x32_bf16(sa_lo[ks], fh[ks], d, 0,0,0);

            float L[4];
            #pragma unroll
            for (int r=0;r<4;++r) L[r] = (2.f*d[r] - s2v[r]) * L2SCALE;
            float mx = fmaxf(fmaxf(L[0],L[1]), fmaxf(L[2],L[3]));
            mx = fmaxf(mx, __shfl_xor(mx, 16));
            mx = fmaxf(mx, __shfl_xor(mx, 32));
            float e[4];
            float z = 0.f;
            #pragma unroll
            for (int r=0;r<4;++r){ e[r] = exp2f(L[r] - mx); z += e[r]; }
            z += __shfl_xor(z, 16);
            z += __shfl_xor(z, 32);
            float rz = 1.f / z;
            #pragma unroll
            for (int r=0;r<4;++r){
                float p = e[r] * rz;
                den_acc[r] += p;
                if (write_attn)
                    attn_out[((size_t)(b*16 + quad*4 + r))*N_ + n0 + hf*128 + nl] = p;
                ushort_t ph = f2bf(p);
                Ph[(quad*4+r)*PSTR + nl] = ph;
                Pl[(quad*4+r)*PSTR + nl] = f2bf(p - bf2f(ph));
            }
        }
        __syncthreads();

        // ---- phase 2 (LDS only): num^T[h][s] += fT_hi*(P_hi+P_lo) + fT_lo*P_hi
        #pragma unroll
        for (int ht2=0; ht2<2; ++ht2){
            const int ht = w*2 + ht2;
            #pragma unroll
            for (int ks=0; ks<4; ++ks){
                short8 ah = ld8x2(&fTh[(ht*16 + ln)*FTSTR + ks*32 + quad*8]);
                short8 al = ld8x2(&fTl[(ht*16 + ln)*FTSTR + ks*32 + quad*8]);
                short8 bh = ld8x2(&Ph[ln*PSTR + ks*32 + quad*8]);
                short8 bl = ld8x2(&Pl[ln*PSTR + ks*32 + quad*8]);
                dacc[ht2] = __builtin_amdgcn_mfma_f32_16x16x32_bf16(ah, bh, dacc[ht2], 0,0,0);
                dacc[ht2] = __builtin_amdgcn_mfma_f32_16x16x32_bf16(ah, bl, dacc[ht2], 0,0,0);
                dacc[ht2] = __builtin_amdgcn_mfma_f32_16x16x32_bf16(al, bh, dacc[ht2], 0,0,0);
            }
        }
    }

    // D layout (phase 2): col = s = ln, row = h-in-tile = quad*4+r
    {
        float* dst = pn + (size_t)blockIdx.x * 2048;
        #pragma unroll
        for (int ht2=0; ht2<2; ++ht2){
            const int ht = w*2 + ht2;
            *(float4*)(dst + ln*128 + ht*16 + quad*4) =
                make_float4(dacc[ht2][0], dacc[ht2][1], dacc[ht2][2], dacc[ht2][3]);
        }
    }

    // den: reduce over n (ln dim), LDS-accumulate, store
    #pragma unroll
    for (int m=1; m<16; m<<=1){
        #pragma unroll
        for (int r=0;r<4;++r) den_acc[r] += __shfl_xor(den_acc[r], m);
    }
    if (ln == 0){
        #pragma unroll
        for (int r=0;r<4;++r) atomicAdd(&den_red[quad*4 + r], den_acc[r]);
    }
    __syncthreads();
    if (tid < 16) pd[blockIdx.x*16 + tid] = den_red[tid];
}

// ---------------------------------------------------------------------------
// update: GRU + LN + MLP + fold of the 32 per-chunk partials. (unchanged)
// ---------------------------------------------------------------------------
__global__ __launch_bounds__(256) void update_kernel(
    const float* __restrict__ pn, const float* __restrict__ pd,
    float* __restrict__ slots,
    const float* __restrict__ gwi, const float* __restrict__ gwh,
    const float* __restrict__ gbi, const float* __restrict__ gbh,
    const float* __restrict__ mw1, const float* __restrict__ mb1,
    const float* __restrict__ mw2, const float* __restrict__ mb2,
    const float* __restrict__ ng, const float* __restrict__ nbv,
    float* __restrict__ out_slots, const int write_out)
{
    __shared__ float us[512], sl[512], gbuf[3072], nbuf[512], lnb[512], qb[512];
    const int tid  = threadIdx.x;
    const int row0 = blockIdx.x * 4;

    for (int i = tid; i < 512; i += 256){
        int r = i >> 7, h = i & 127;
        int grow = row0 + r;
        int bb = grow >> 4, ss = grow & 15;
        float sum = 0.f, dv = 0.f;
        #pragma unroll 4
        for (int c = 0; c < NBLK; ++c)
            sum += pn[((size_t)(bb*NBLK + c))*2048 + ss*128 + h];
        #pragma unroll
        for (int c = 0; c < NBLK; ++c)
            dv += pd[(bb*NBLK + c)*16 + ss];
        us[i] = sum / (dv + 1e-8f);
        sl[i] = slots[(size_t)grow*128 + h];
    }
    __syncthreads();

    for (int idx = tid; idx < 3072; idx += 256){
        int which = idx >= 1536;
        int rem   = idx - which*1536;
        int r     = rem / 384;
        int o     = rem - r*384;
        const float* W   = which ? gwh : gwi;
        const float* bb  = which ? gbh : gbi;
        const float* src = (which ? sl : us) + r*128;
        float a = bb[o];
        const float4* Wr = (const float4*)(W + (size_t)o*128);
        #pragma unroll 8
        for (int k4=0;k4<32;++k4){
            float4 wv = Wr[k4];
            float4 sv = *(const float4*)(src + 4*k4);
            a += sv.x*wv.x + sv.y*wv.y + sv.z*wv.z + sv.w*wv.w;
        }
        gbuf[idx] = a;
    }
    __syncthreads();

    for (int i = tid; i < 512; i += 256){
        int r = i >> 7, h = i & 127;
        float ir  = gbuf[r*384 + h];
        float iz  = gbuf[r*384 + 128 + h];
        float in_ = gbuf[r*384 + 256 + h];
        float hr  = gbuf[1536 + r*384 + h];
        float hz  = gbuf[1536 + r*384 + 128 + h];
        float hn  = gbuf[1536 + r*384 + 256 + h];
        float rg = 1.f/(1.f + __expf(-(ir+hr)));
        float zg = 1.f/(1.f + __expf(-(iz+hz)));
        float nn = tanhf(in_ + rg*hn);
        nbuf[i] = (1.f - zg)*nn + zg*sl[i];
    }
    __syncthreads();

    {
        int wv = tid >> 6, ll = tid & 63;
        float v0 = nbuf[wv*128 + ll], v1 = nbuf[wv*128 + 64 + ll];
        float s1 = v0 + v1, sq = v0*v0 + v1*v1;
        #pragma unroll
        for (int m=1; m<64; m<<=1){ s1 += __shfl_xor(s1,m); sq += __shfl_xor(sq,m); }
        float mean = s1*(1.f/128.f), var = sq*(1.f/128.f) - mean*mean;
        float rs = 1.f/sqrtf(var + 1e-5f);
        lnb[wv*128 + ll]      = (v0-mean)*rs*ng[ll] + nbv[ll];
        lnb[wv*128 + 64 + ll] = (v1-mean)*rs*ng[64+ll] + nbv[64+ll];
    }
    __syncthreads();

    for (int i = tid; i < 512; i += 256){
        int r = i >> 7, o = i & 127;
        float a = mb1[o];
        const float* lr = lnb + r*128;
        #pragma unroll 8
        for (int k=0;k<128;++k) a += lr[k] * mw1[(size_t)k*128 + o];
        qb[i] = gelu_fast(a);
    }
    __syncthreads();

    for (int i = tid; i < 512; i += 256){
        int r = i >> 7, h = i & 127;
        float a = mb2[h];
        const float* qr = qb + r*128;
        #pragma unroll 8
        for (int k=0;k<128;++k) a += qr[k] * mw2[(size_t)k*128 + h];
        float ov = nbuf[i] + 0.2f*a;
        int grow = row0 + r;
        slots[(size_t)grow*128 + h] = ov;
        if (write_out) out_slots[(size_t)grow*128 + h] = ov;
    }
}

// ---------------------------------------------------------------------------
extern "C" void kernel_launch(void* const* d_in, const int* in_sizes, int n_in,
                              void* d_out, int out_size, void* d_ws, size_t ws_size,
                              hipStream_t stream)
{
    const float* x    = (const float*)d_in[0];
    const float* w1   = (const float*)d_in[1];
    const float* b1   = (const float*)d_in[2];
    const float* ln1g = (const float*)d_in[3];
    const float* ln1b = (const float*)d_in[4];
    const float* w2   = (const float*)d_in[5];
    const float* b2   = (const float*)d_in[6];
    const float* ln2g = (const float*)d_in[7];
    const float* ln2b = (const float*)d_in[8];
    const float* smu  = (const float*)d_in[9];
    const float* gwi  = (const float*)d_in[10];
    const float* gwh  = (const float*)d_in[11];
    const float* gbi  = (const float*)d_in[12];
    const float* gbh  = (const float*)d_in[13];
    const float* mw1  = (const float*)d_in[14];
    const float* mb1  = (const float*)d_in[15];
    const float* mw2  = (const float*)d_in[16];
    const float* mb2  = (const float*)d_in[17];
    const float* ng   = (const float*)d_in[18];
    const float* nbv  = (const float*)d_in[19];

    float* out_slots = (float*)d_out;
    float* out_attn  = (float*)d_out + (size_t)B_*S_*H_;

    ushort_t* f_hi = (ushort_t*)d_ws;                       // 64 MB
    ushort_t* f_lo = f_hi + (size_t)B_*N_*H_;               // 64 MB
    float* slots = (float*)(f_lo + (size_t)B_*N_*H_);       // 256 KB
    float* pn    = slots + B_*S_*H_;                        // 1024*2048 fp32 = 8 MB
    float* pd    = pn + (size_t)(B_*NBLK)*2048;             // 64 KB
    ushort_t* w1t_hi = (ushort_t*)(pd + B_*NBLK*16);
    ushort_t* w1t_lo = w1t_hi + 8192;
    ushort_t* w2t_hi = w1t_lo + 8192;
    ushort_t* w2t_lo = w2t_hi + 16384;

    prep_kernel<<<dim3(64), dim3(256), 0, stream>>>(w1, w2, w1t_hi, w1t_lo, w2t_hi, w2t_lo);
    feats_kernel<<<dim3(2048), dim3(256), 0, stream>>>(
        x, w1t_hi, w1t_lo, w2t_hi, w2t_lo, b1, ln1g, ln1b, b2, ln2g, ln2b, f_hi, f_lo);
    init_slots<<<dim3(256), dim3(256), 0, stream>>>(smu, slots);

    for (int it = 0; it < 3; ++it){
        attn_kernel<<<dim3(B_*NBLK), dim3(256), 0, stream>>>(
            f_hi, f_lo, slots, pn, pd, out_attn, (it==2) ? 1 : 0);
        update_kernel<<<dim3(128), dim3(256), 0, stream>>>(
            pn, pd, slots, gwi, gwh, gbi, gbh, mw1, mb1, mw2, mb2, ng, nbv,
            out_slots, (it==2) ? 1 : 0);
    }
}